// Round 5
// baseline (805.260 us; speedup 1.0000x reference)
//
#include <hip/hip_runtime.h>

#define NUSERS 100000
#define NITEMS 50000
#define NNODES 150000
#define DIM 64
#define E0 600000
#define E2 (2 * E0)
#define BB 8192
#define LW 1e-4f
#define NN16 150016

// ---- counting-sort CSR build ----
#define NBUCK 1172      // ceil(NNODES / 128): bucket = node >> 7
#define CHUNK_E 2048
#define CHUNKS 293      // ceil(E0 / CHUNK_E); NBUCK == 4*CHUNKS
#define CPAD 320        // padded chunk stride in cnt matrix (bucket-major)
#define BCAP 2048       // LDS staging cap per bucket (max observed ~1.8K; global fallback)

// ---- persistent-kernel grids (must be <= co-residency capacity) ----
#define NB_A 1172       // build kernel blocks (256 thr, 18.4KB LDS, vgpr<=64 -> cap 2048)
#define NB_B 768        // main kernel blocks (512 thr, vgpr<=64 -> cap 1024)
#define TH_B 512
#define NTHR_B (NB_B * TH_B)   // 393216

// ---- bf16 helpers ----
__device__ __forceinline__ float bf_lo(unsigned u) { return __uint_as_float(u << 16); }
__device__ __forceinline__ float bf_hi(unsigned u) { return __uint_as_float(u & 0xffff0000u); }
__device__ __forceinline__ unsigned rne16(float x) {
  unsigned u = __float_as_uint(x);
  return (u + 0x7fffu + ((u >> 16) & 1u)) >> 16;
}
__device__ __forceinline__ unsigned pack2(float lo, float hi) {
  return rne16(lo) | (rne16(hi) << 16);
}

// NOTE: param not named x/y/z/w (macro substitution hits member accesses).
#define ACC8(X) do { \
    a0 += bf_lo((X).x); a1 += bf_hi((X).x); a2 += bf_lo((X).y); a3 += bf_hi((X).y); \
    a4 += bf_lo((X).z); a5 += bf_hi((X).z); a6 += bf_lo((X).w); a7 += bf_hi((X).w); \
  } while (0)

// ---- manual grid barrier (persistent-kernel pattern) ----
// All blocks call it the same number of times; counter is monotonic.
__device__ __forceinline__ void gbar(int* bar, int target) {
  __syncthreads();
  if (threadIdx.x == 0) {
    __threadfence();                      // release: drain stores to coherence point
    atomicAdd(bar, 1);
    while (__hip_atomic_load(bar, __ATOMIC_RELAXED, __HIP_MEMORY_SCOPE_AGENT) < target)
      __builtin_amdgcn_s_sleep(8);
    __threadfence();                      // acquire: invalidate stale cached lines
  }
  __syncthreads();
}

// =====================================================================
// Kernel A: whole CSR build, 4 phases, 3 grid barriers.
// =====================================================================
__global__ __launch_bounds__(256, 8) void k_build(
    const int* __restrict__ eu, const int* __restrict__ ei,
    int* __restrict__ cnt, int* __restrict__ btot,
    int* __restrict__ deg, int* __restrict__ ptr, float* __restrict__ dinv,
    int* __restrict__ col, unsigned* __restrict__ pk,
    const float4* __restrict__ Gu4, const float4* __restrict__ Gi4,
    uint2* __restrict__ h0, int* __restrict__ barA) {
  __shared__ int smemi[4608];   // 18432 B, reused per phase
  int bid = blockIdx.x, tid = threadIdx.x;

  // ---- P1: per-chunk LDS histogram of bucket counts ----
  if (bid < CHUNKS) {
    int* h = smemi;
    for (int i = tid; i < NBUCK; i += 256) h[i] = 0;
    __syncthreads();
    int e0 = bid * CHUNK_E, e1 = min(e0 + CHUNK_E, E0);
    for (int e = e0 + tid; e < e1; e += 256) {
      atomicAdd(&h[eu[e] >> 7], 1);
      atomicAdd(&h[(NUSERS + ei[e]) >> 7], 1);
    }
    __syncthreads();
    for (int i = tid; i < NBUCK; i += 256) cnt[(size_t)i * CPAD + bid] = h[i];
  }
  gbar(barA, NB_A);

  // ---- P2: per-bucket exclusive scan over chunks + bucket totals ----
  if (bid < CHUNKS) {
    int b = bid * 4 + (tid >> 6);
    int lane = tid & 63;
    int* row = cnt + (size_t)b * CPAD;
    int carry = 0;
    for (int c0 = 0; c0 < CHUNKS; c0 += 64) {
      int c = c0 + lane;
      int v = (c < CHUNKS) ? row[c] : 0;
      int s = v;
      #pragma unroll
      for (int m = 1; m < 64; m <<= 1) {
        int t = __shfl_up(s, m);
        if (lane >= m) s += t;
      }
      if (c < CHUNKS) row[c] = carry + s - v;
      carry += __shfl(s, 63);
    }
    if (lane == 63) btot[b] = carry;
  }
  gbar(barA, 2 * NB_A);

  // ---- P3: scatter. Each chunk-block privately scans btot -> bbase,
  //      adds its cnt column -> per-bucket cursors, LDS-atomic scatter. ----
  if (bid < CHUNKS) {
    int* S = smemi;          // [1280] padded scan array
    int* T = smemi + 1280;   // [256] per-thread block sums
    for (int i = tid; i < 1280; i += 256) S[i] = (i < NBUCK) ? btot[i] : 0;
    __syncthreads();
    int b0 = tid * 5;
    int run = 0;
    #pragma unroll
    for (int k = 0; k < 5; k++) { run += S[b0 + k]; S[b0 + k] = run; }  // inclusive
    T[tid] = run;
    __syncthreads();
    for (int off = 1; off < 256; off <<= 1) {
      int t = 0;
      if (tid >= off) t = T[tid - off];
      __syncthreads();
      if (tid >= off) T[tid] += t;
      __syncthreads();
    }
    int texc = T[tid] - run;                        // exclusive across threads
    for (int k = 4; k >= 0; k--)                    // -> global exclusive, in place
      S[b0 + k] = texc + (k ? S[b0 + k - 1] : 0);
    __syncthreads();
    // soff = bbase + this chunk's window offset
    for (int i = tid; i < NBUCK; i += 256) S[i] += cnt[(size_t)i * CPAD + bid];
    __syncthreads();
    int e0 = bid * CHUNK_E, e1 = min(e0 + CHUNK_E, E0);
    for (int e = e0 + tid; e < e1; e += 256) {
      int u = eu[e];
      int it = NUSERS + ei[e];
      int s1 = atomicAdd(&S[u >> 7], 1);
      pk[s1] = ((unsigned)it << 7) | (unsigned)(u & 127);
      int s2 = atomicAdd(&S[it >> 7], 1);
      pk[s2] = ((unsigned)u << 7) | (unsigned)(it & 127);
    }
  }
  gbar(barA, 3 * NB_A);

  // ---- P4: one block per bucket: deg/ptr/dinv, LDS-ranked col, scaled cast ----
  {
    int b = bid;
    // base = sum btot[0..b-1] via block reduce (reuses smemi[0..255])
    int part = 0;
    for (int i = tid; i < b; i += 256) part += btot[i];
    smemi[tid] = part;
    __syncthreads();
    for (int off = 128; off > 0; off >>= 1) {
      if (tid < off) smemi[tid] += smemi[tid + off];
      __syncthreads();
    }
    int base = smemi[0];
    int n = btot[b];
    __syncthreads();   // done with reduce area before reuse

    unsigned* sitm = (unsigned*)smemi;        // [2048]
    int* lcol  = smemi + 2048;                // [2048]
    int* ldeg  = smemi + 4096;                // [128]
    int* lscan = smemi + 4224;                // [128]
    int* lcnt  = smemi + 4352;                // [128]
    float* sdv = (float*)(smemi + 4480);      // [128]

    for (int i = tid; i < n; i += 256)
      if (i < BCAP) sitm[i] = pk[base + i];
    if (tid < 128) { ldeg[tid] = 0; lcnt[tid] = 0; }
    __syncthreads();
    for (int i = tid; i < n; i += 256) {
      unsigned p = (i < BCAP) ? sitm[i] : pk[base + i];
      atomicAdd(&ldeg[p & 127], 1);
    }
    __syncthreads();
    if (tid < 128) lscan[tid] = ldeg[tid];
    __syncthreads();
    for (int off = 1; off < 128; off <<= 1) {
      int t = 0;
      if (tid < 128 && tid >= off) t = lscan[tid - off];
      __syncthreads();
      if (tid < 128 && tid >= off) lscan[tid] += t;
      __syncthreads();
    }
    int node = b * 128 + tid;
    if (tid < 128) {
      int d = ldeg[tid];
      lscan[tid] -= d;                     // -> exclusive (bucket-local)
      float dv = d > 0 ? rsqrtf((float)d) : 0.0f;
      sdv[tid] = dv;
      if (node < NNODES) {
        deg[node] = d;
        ptr[node] = base + lscan[tid];
        dinv[node] = dv;
      }
    }
    __syncthreads();
    for (int i = tid; i < n; i += 256) {
      unsigned p = (i < BCAP) ? sitm[i] : pk[base + i];
      int dl = p & 127;
      int nb = (int)(p >> 7);
      int dnode = b * 128 + dl;
      int val = (dnode < NUSERS) ? nb - NUSERS : nb;   // opposite-half-local id
      int rel = lscan[dl] + atomicAdd(&lcnt[dl], 1);
      if (rel < BCAP) lcol[rel] = val;
      else col[base + rel] = val;
    }
    __syncthreads();
    int nf = min(n, BCAP);
    for (int i = tid; i < nf; i += 256) col[base + i] = lcol[i];
    // scaled cast: h0 = bf16(dinv * G)
    for (int w = tid; w < 128 * 16; w += 256) {
      int nl = w >> 4, q = w & 15;
      int nd = b * 128 + nl;
      if (nd < NNODES) {
        float dv = sdv[nl];
        float4 v = (nd < NUSERS) ? Gu4[(size_t)nd * 16 + q]
                                 : Gi4[(size_t)(nd - NUSERS) * 16 + q];
        h0[(size_t)nd * 16 + q] =
            make_uint2(pack2(dv * v.x, dv * v.y), pack2(dv * v.z, dv * v.w));
      }
    }
  }
}

// ---- SpMM body: 8 lanes per node, sequential neighbors, 4x unrolled ----
__device__ __forceinline__ void spmm_node(
    int g, int q, const uint4* __restrict__ hq, int st, int dg, float dn,
    uint4* __restrict__ dst) {
  float a0 = 0, a1 = 0, a2 = 0, a3 = 0, a4 = 0, a5 = 0, a6 = 0, a7 = 0;
  extern __device__ int dummy_;  // (no-op; keeps signature simple)
  (void)dummy_;
  int jend = st + dg;
  int j = st;
  // col pointer is passed via hq trick impossible; handled by caller loops below
  (void)j; (void)jend;
  (void)a0;(void)a1;(void)a2;(void)a3;(void)a4;(void)a5;(void)a6;(void)a7;
  (void)g; (void)q; (void)dn; (void)dst;
}

#define SPMM_BODY(COLP, HQ, DSTP, DSTIDX)                                    \
  do {                                                                       \
    float a0 = 0, a1 = 0, a2 = 0, a3 = 0, a4 = 0, a5 = 0, a6 = 0, a7 = 0;    \
    int jend = st + dg;                                                      \
    int j = st;                                                              \
    for (; j + 4 <= jend; j += 4) {                                          \
      int c0 = (COLP)[j], c1 = (COLP)[j + 1], c2 = (COLP)[j + 2], c3 = (COLP)[j + 3]; \
      uint4 x0 = (HQ)[(size_t)c0 * 8];                                       \
      uint4 x1 = (HQ)[(size_t)c1 * 8];                                       \
      uint4 x2 = (HQ)[(size_t)c2 * 8];                                       \
      uint4 x3 = (HQ)[(size_t)c3 * 8];                                       \
      ACC8(x0); ACC8(x1); ACC8(x2); ACC8(x3);                                \
    }                                                                        \
    if (j + 2 <= jend) {                                                     \
      int c0 = (COLP)[j], c1 = (COLP)[j + 1];                                \
      uint4 x0 = (HQ)[(size_t)c0 * 8];                                       \
      uint4 x1 = (HQ)[(size_t)c1 * 8];                                       \
      ACC8(x0); ACC8(x1);                                                    \
      j += 2;                                                                \
    }                                                                        \
    if (j < jend) {                                                          \
      int c0 = (COLP)[j];                                                    \
      uint4 x0 = (HQ)[(size_t)c0 * 8];                                       \
      ACC8(x0);                                                              \
    }                                                                        \
    float s = dn * dn;                                                       \
    (DSTP)[DSTIDX] = make_uint4(pack2(a0 * s, a1 * s), pack2(a2 * s, a3 * s),\
                                pack2(a4 * s, a5 * s), pack2(a6 * s, a7 * s));\
  } while (0)

__device__ __forceinline__ int decode_node(int k, const int* __restrict__ usr,
                                           const int* __restrict__ pos,
                                           const int* __restrict__ neg, int* coff) {
  if (k < BB) { *coff = NUSERS; return usr[k]; }
  if (k < 2 * BB) { *coff = 0; return NUSERS + pos[k - BB]; }
  *coff = 0; return NUSERS + neg[k - 2 * BB];
}

// =====================================================================
// Kernel B: spmm L1, spmm L2, batch spmm L3 (slot-indexed), loss, tail.
// =====================================================================
__global__ __launch_bounds__(512, 8) void k_main(
    const int* __restrict__ ptr, const int* __restrict__ deg,
    const int* __restrict__ col, const float* __restrict__ dinv,
    const int* __restrict__ usr, const int* __restrict__ pos,
    const int* __restrict__ neg,
    const float4* __restrict__ Gu4, const float4* __restrict__ Gi4,
    const uint4* __restrict__ h0, uint4* __restrict__ h1, uint4* __restrict__ h2,
    uint4* __restrict__ e3, float* __restrict__ bpart, float* __restrict__ out,
    int* __restrict__ barB, int* __restrict__ done) {
  int tid = threadIdx.x, bid = blockIdx.x;
  int gt = bid * TH_B + tid;

  // ---- P1: h1 = S(h0) over all nodes ----
  for (int idx = gt; idx < NNODES * 8; idx += NTHR_B) {
    int g = idx >> 3, q = idx & 7;
    const uint4* hq = ((g < NUSERS) ? h0 + (size_t)NUSERS * 8 : h0) + q;
    int st = ptr[g], dg = deg[g];
    float dn = dinv[g];
    SPMM_BODY(col, hq, h1, (size_t)g * 8 + q);
  }
  gbar(barB, NB_B);

  // ---- P2: h2 = S(h1) ----
  for (int idx = gt; idx < NNODES * 8; idx += NTHR_B) {
    int g = idx >> 3, q = idx & 7;
    const uint4* hq = ((g < NUSERS) ? h1 + (size_t)NUSERS * 8 : h1) + q;
    int st = ptr[g], dg = deg[g];
    float dn = dinv[g];
    SPMM_BODY(col, hq, h2, (size_t)g * 8 + q);
  }
  gbar(barB, 2 * NB_B);

  // ---- P3: e3[slot] = S(h2) at batch slots (slot-indexed, coalesced) ----
  for (int idx = gt; idx < 3 * BB * 8; idx += NTHR_B) {
    int k = idx >> 3, q = idx & 7;
    int coff;
    int g = decode_node(k, usr, pos, neg, &coff);
    const uint4* hq = h2 + (size_t)coff * 8 + q;
    int st = ptr[g], dg = deg[g];
    float dn = dinv[g];
    SPMM_BODY(col, hq, e3, (size_t)k * 8 + q);
  }
  gbar(barB, 3 * NB_B);

  // ---- P4: fused gather + layer sum + BPR loss ----
  {
    __shared__ float sL[8], sR[8];
    const uint2* h1u = (const uint2*)h1;
    const uint2* h2u = (const uint2*)h2;
    const uint2* e3u = (const uint2*)e3;
    int wid = tid >> 6, lane = tid & 63, r = lane >> 4, q = lane & 15;
    int gw = bid * 8 + wid;
    const float s = 0.25f;
    float accL = 0.0f, accR = 0.0f;
    for (int b4 = gw; b4 < BB / 4; b4 += NB_B * 8) {
      int b = b4 * 4 + r;
      int iu = usr[b], ip = pos[b], ig = neg[b];
      float sdu = sqrtf((float)deg[iu]);
      float sdp = sqrtf((float)deg[NUSERS + ip]);
      float sdn = sqrtf((float)deg[NUSERS + ig]);
      size_t ou = (size_t)iu * 16 + q;
      size_t op = ((size_t)NUSERS + ip) * 16 + q;
      size_t on = ((size_t)NUSERS + ig) * 16 + q;
      float4 u = Gu4[ou];
      float4 p = Gi4[(size_t)ip * 16 + q];
      float4 g = Gi4[(size_t)ig * 16 + q];
      float4 su = {0, 0, 0, 0}, sp = {0, 0, 0, 0}, sg = {0, 0, 0, 0};
      uint2 v;
      v = h1u[ou]; su.x += bf_lo(v.x); su.y += bf_hi(v.x); su.z += bf_lo(v.y); su.w += bf_hi(v.y);
      v = h2u[ou]; su.x += bf_lo(v.x); su.y += bf_hi(v.x); su.z += bf_lo(v.y); su.w += bf_hi(v.y);
      v = e3u[(size_t)b * 16 + q];
      su.x += bf_lo(v.x); su.y += bf_hi(v.x); su.z += bf_lo(v.y); su.w += bf_hi(v.y);
      v = h1u[op]; sp.x += bf_lo(v.x); sp.y += bf_hi(v.x); sp.z += bf_lo(v.y); sp.w += bf_hi(v.y);
      v = h2u[op]; sp.x += bf_lo(v.x); sp.y += bf_hi(v.x); sp.z += bf_lo(v.y); sp.w += bf_hi(v.y);
      v = e3u[((size_t)BB + b) * 16 + q];
      sp.x += bf_lo(v.x); sp.y += bf_hi(v.x); sp.z += bf_lo(v.y); sp.w += bf_hi(v.y);
      v = h1u[on]; sg.x += bf_lo(v.x); sg.y += bf_hi(v.x); sg.z += bf_lo(v.y); sg.w += bf_hi(v.y);
      v = h2u[on]; sg.x += bf_lo(v.x); sg.y += bf_hi(v.x); sg.z += bf_lo(v.y); sg.w += bf_hi(v.y);
      v = e3u[((size_t)2 * BB + b) * 16 + q];
      sg.x += bf_lo(v.x); sg.y += bf_hi(v.x); sg.z += bf_lo(v.y); sg.w += bf_hi(v.y);
      u.x = (u.x + sdu * su.x) * s; u.y = (u.y + sdu * su.y) * s;
      u.z = (u.z + sdu * su.z) * s; u.w = (u.w + sdu * su.w) * s;
      p.x = (p.x + sdp * sp.x) * s; p.y = (p.y + sdp * sp.y) * s;
      p.z = (p.z + sdp * sp.z) * s; p.w = (p.w + sdp * sp.w) * s;
      g.x = (g.x + sdn * sg.x) * s; g.y = (g.y + sdn * sg.y) * s;
      g.z = (g.z + sdn * sg.z) * s; g.w = (g.w + sdn * sg.w) * s;
      float dp = u.x * p.x + u.y * p.y + u.z * p.z + u.w * p.w;
      float dn = u.x * g.x + u.y * g.y + u.z * g.z + u.w * g.w;
      float rg = u.x * u.x + u.y * u.y + u.z * u.z + u.w * u.w
               + p.x * p.x + p.y * p.y + p.z * p.z + p.w * p.w
               + g.x * g.x + g.y * g.y + g.z * g.z + g.w * g.w;
      #pragma unroll
      for (int m = 1; m <= 8; m <<= 1) {
        dp += __shfl_xor(dp, m);
        dn += __shfl_xor(dn, m);
        rg += __shfl_xor(rg, m);
      }
      if (q == 0) {
        float diff = dp - dn;
        accL -= fminf(diff, 0.0f) - log1pf(expf(-fabsf(diff)));
        accR += rg;
      }
    }
    accL += __shfl_xor(accL, 16); accR += __shfl_xor(accR, 16);
    accL += __shfl_xor(accL, 32); accR += __shfl_xor(accR, 32);
    if (lane == 0) { sL[wid] = accL; sR[wid] = accR; }
    __syncthreads();
    if (tid == 0) {
      float l = 0, rr = 0;
      #pragma unroll
      for (int w = 0; w < 8; w++) { l += sL[w]; rr += sR[w]; }
      bpart[bid] = l;
      bpart[NB_B + bid] = rr;
    }
  }

  // ---- tail: last-done block reduces bpart -> out (deterministic order) ----
  __shared__ int lastFlag;
  if (tid == 0) {
    __threadfence();
    int d = atomicAdd(done, 1);
    lastFlag = (d == NB_B - 1) ? 1 : 0;
  }
  __syncthreads();
  if (lastFlag) {
    __threadfence();
    if (tid < 64) {
      float l = 0.0f, r = 0.0f;
      for (int i = tid; i < NB_B; i += 64) {
        l += bpart[i];
        r += bpart[NB_B + i];
      }
      for (int off = 32; off > 0; off >>= 1) {
        l += __shfl_down(l, off);
        r += __shfl_down(r, off);
      }
      if (tid == 0) out[0] = l * (1.0f / BB) + LW * 0.5f * r * (1.0f / BB);
    }
  }
}

extern "C" void kernel_launch(void* const* d_in, const int* in_sizes, int n_in,
                              void* d_out, int out_size, void* d_ws, size_t ws_size,
                              hipStream_t stream) {
  const float* Gu = (const float*)d_in[0];
  const float* Gi = (const float*)d_in[1];
  const int* eu  = (const int*)d_in[2];
  const int* ei  = (const int*)d_in[3];
  const int* usr = (const int*)d_in[4];
  const int* pos = (const int*)d_in[5];
  const int* neg = (const int*)d_in[6];
  float* out = (float*)d_out;

  // Workspace layout (same as R4); build scratch aliases not-yet-live h buffers.
  int* deg    = (int*)d_ws;                  // NN16
  int* ptr    = deg + NN16;                  // NN16
  float* dinv = (float*)(ptr + NN16);        // NN16
  int* col    = (int*)(dinv + NN16);         // E2
  uint2* h0   = (uint2*)(col + E2);          // NNODES*16 uint2 each (19.2 MB)
  uint2* h1   = h0 + (size_t)NNODES * 16;
  uint2* h2   = h1 + (size_t)NNODES * 16;
  uint2* h3   = h2 + (size_t)NNODES * 16;    // e3 (slot-indexed, 3 MB) lives here
  float* bpart = (float*)(h3 + (size_t)NNODES * 16);  // 2*NB_B floats
  int* bars   = (int*)(bpart + 2 * NB_B);    // barA, barB, done

  unsigned* pk = (unsigned*)h1;              // E2 (scattered directed edges)
  int* cnt     = (int*)h2;                   // NBUCK * CPAD
  int* btot    = (int*)h3;                   // NBUCK (dead before e3 is written)

  const float4* Gu4 = (const float4*)Gu;
  const float4* Gi4 = (const float4*)Gi;

  hipMemsetAsync(bars, 0, 12, stream);       // barA, barB, done = 0

  k_build<<<NB_A, 256, 0, stream>>>(eu, ei, cnt, btot, deg, ptr, dinv, col, pk,
                                    Gu4, Gi4, h0, bars);

  k_main<<<NB_B, TH_B, 0, stream>>>(ptr, deg, col, dinv, usr, pos, neg, Gu4, Gi4,
                                    (const uint4*)h0, (uint4*)h1, (uint4*)h2,
                                    (uint4*)h3, bpart, out, bars + 1, bars + 2);
}

// Round 7
// 198.128 us; speedup vs baseline: 4.0643x; 4.0643x over previous
//
#include <hip/hip_runtime.h>

#define NUSERS 100000
#define NITEMS 50000
#define NNODES 150000
#define DIM 64
#define E0 600000
#define E2 (2 * E0)
#define BB 8192
#define LW 1e-4f
#define NN16 150016
#define SPMM_B 2344    // ceil(NNODES*8 / 512)
#define LOSS3_B 512    // 16 batch elements per block

// ---- counting-sort CSR build (no device-scope atomics) ----
#define NBUCK 1172      // ceil(NNODES / 128): bucket = node >> 7
#define CHUNK_E 2048    // edges per chunk
#define CHUNKS 293      // ceil(E0 / CHUNK_E)
#define CPAD 320        // padded chunk stride in cnt matrix (bucket-major)
#define BCAP 3072       // LDS staging cap per bucket (max observed ~1.7K)

// ---- bf16 helpers (fp32 <-> packed bf16 pair in a uint) ----
__device__ __forceinline__ float bf_lo(unsigned u) { return __uint_as_float(u << 16); }
__device__ __forceinline__ float bf_hi(unsigned u) { return __uint_as_float(u & 0xffff0000u); }
__device__ __forceinline__ unsigned rne16(float x) {
  unsigned u = __float_as_uint(x);
  return (u + 0x7fffu + ((u >> 16) & 1u)) >> 16;
}
__device__ __forceinline__ unsigned pack2(float lo, float hi) {
  return rne16(lo) | (rne16(hi) << 16);
}

// NOTE (macro hygiene, R3/R6 compile failures): param not named x/y/z/w;
// all internals suffixed _ ; DSTIDX evaluated FIRST (before any internal
// declaration could shadow caller identifiers).
#define ACC8(X) do { \
    a0 += bf_lo((X).x); a1 += bf_hi((X).x); a2 += bf_lo((X).y); a3 += bf_hi((X).y); \
    a4 += bf_lo((X).z); a5 += bf_hi((X).z); a6 += bf_lo((X).w); a7 += bf_hi((X).w); \
  } while (0)

// 8 lanes per node row; sequential neighbors, 4x unrolled (4 gathers in flight).
#define SPMM_BODY(COLP, HQ, DSTP, DSTIDX)                                    \
  do {                                                                       \
    const int dsti_ = (DSTIDX);                                              \
    float a0 = 0, a1 = 0, a2 = 0, a3 = 0, a4 = 0, a5 = 0, a6 = 0, a7 = 0;    \
    int jend_ = st + dg;                                                     \
    int j_ = st;                                                             \
    for (; j_ + 4 <= jend_; j_ += 4) {                                       \
      int c0_ = (COLP)[j_], c1_ = (COLP)[j_ + 1];                            \
      int c2_ = (COLP)[j_ + 2], c3_ = (COLP)[j_ + 3];                        \
      uint4 x0_ = (HQ)[(size_t)c0_ * 8];                                     \
      uint4 x1_ = (HQ)[(size_t)c1_ * 8];                                     \
      uint4 x2_ = (HQ)[(size_t)c2_ * 8];                                     \
      uint4 x3_ = (HQ)[(size_t)c3_ * 8];                                     \
      ACC8(x0_); ACC8(x1_); ACC8(x2_); ACC8(x3_);                            \
    }                                                                        \
    if (j_ + 2 <= jend_) {                                                   \
      int c0_ = (COLP)[j_], c1_ = (COLP)[j_ + 1];                            \
      uint4 x0_ = (HQ)[(size_t)c0_ * 8];                                     \
      uint4 x1_ = (HQ)[(size_t)c1_ * 8];                                     \
      ACC8(x0_); ACC8(x1_);                                                  \
      j_ += 2;                                                               \
    }                                                                        \
    if (j_ < jend_) {                                                        \
      int c0_ = (COLP)[j_];                                                  \
      uint4 x0_ = (HQ)[(size_t)c0_ * 8];                                     \
      ACC8(x0_);                                                             \
    }                                                                        \
    float scl_ = dn * dn;                                                    \
    (DSTP)[dsti_] = make_uint4(pack2(a0 * scl_, a1 * scl_),                  \
                               pack2(a2 * scl_, a3 * scl_),                  \
                               pack2(a4 * scl_, a5 * scl_),                  \
                               pack2(a6 * scl_, a7 * scl_));                 \
  } while (0)

// Pass 1: per-chunk LDS histogram of bucket counts.
// cnt is bucket-major: cnt[b*CPAD + c] so the per-bucket scan is coalesced.
__global__ __launch_bounds__(256) void k_bcount(const int* __restrict__ eu,
                                                const int* __restrict__ ei,
                                                int* __restrict__ cnt) {
  __shared__ int h[NBUCK];
  for (int i = threadIdx.x; i < NBUCK; i += 256) h[i] = 0;
  __syncthreads();
  int c = blockIdx.x;
  int e0 = c * CHUNK_E;
  int e1 = min(e0 + CHUNK_E, E0);
  for (int e = e0 + threadIdx.x; e < e1; e += 256) {
    int u = eu[e];
    int it = NUSERS + ei[e];
    atomicAdd(&h[u >> 7], 1);
    atomicAdd(&h[it >> 7], 1);
  }
  __syncthreads();
  for (int i = threadIdx.x; i < NBUCK; i += 256) cnt[(size_t)i * CPAD + c] = h[i];
}

// Pass 2: per-bucket exclusive scan over chunks (wave per bucket, in place)
// + bucket totals. Lane loads are coalesced (bucket-major layout).
__global__ __launch_bounds__(256) void k_bscan1(int* __restrict__ cnt,
                                                int* __restrict__ btot) {
  int b = blockIdx.x * 4 + (threadIdx.x >> 6);   // grid = CHUNKS blocks (NBUCK/4)
  int lane = threadIdx.x & 63;
  int* row = cnt + (size_t)b * CPAD;
  int carry = 0;
  for (int c0 = 0; c0 < CHUNKS; c0 += 64) {
    int c = c0 + lane;
    int v = (c < CHUNKS) ? row[c] : 0;
    int s = v;
    #pragma unroll
    for (int m = 1; m < 64; m <<= 1) {
      int t = __shfl_up(s, m);
      if (lane >= m) s += t;
    }
    if (c < CHUNKS) row[c] = carry + s - v;      // exclusive within bucket
    carry += __shfl(s, 63);
  }
  if (lane == 63) btot[b] = carry;
}

// Pass 3: scatter directed edges into bucket regions. Each block privately
// scans btot -> bbase in LDS (deletes the old k_bbase dispatch); block 0
// publishes bbase for k_bucket_csr. LDS atomics only.
// Payload: (neighbor_id << 7) | (dst & 127).
__global__ __launch_bounds__(256) void k_bscatter(const int* __restrict__ eu,
                                                  const int* __restrict__ ei,
                                                  const int* __restrict__ cnt,
                                                  const int* __restrict__ btot,
                                                  int* __restrict__ bbase,
                                                  unsigned* __restrict__ pk) {
  __shared__ int S[1280];
  __shared__ int T[256];
  int bid = blockIdx.x, tid = threadIdx.x;
  for (int i = tid; i < 1280; i += 256) S[i] = (i < NBUCK) ? btot[i] : 0;
  __syncthreads();
  int b0 = tid * 5;
  int run = 0;
  #pragma unroll
  for (int k = 0; k < 5; k++) { run += S[b0 + k]; S[b0 + k] = run; }  // inclusive
  T[tid] = run;
  __syncthreads();
  for (int off = 1; off < 256; off <<= 1) {
    int t = 0;
    if (tid >= off) t = T[tid - off];
    __syncthreads();
    if (tid >= off) T[tid] += t;
    __syncthreads();
  }
  int texc = T[tid] - run;                        // exclusive across threads
  for (int k = 4; k >= 0; k--)                    // -> global exclusive, in place
    S[b0 + k] = texc + (k ? S[b0 + k - 1] : 0);
  // publish bbase (block 0 only)
  if (bid == 0)
    for (int i = tid; i < NBUCK; i += 256) bbase[i] = S[i];
  __syncthreads();
  // per-bucket cursor = bbase + this chunk's window offset
  for (int i = tid; i < NBUCK; i += 256) S[i] += cnt[(size_t)i * CPAD + bid];
  __syncthreads();
  int e0 = bid * CHUNK_E, e1 = min(e0 + CHUNK_E, E0);
  for (int e = e0 + tid; e < e1; e += 256) {
    int u = eu[e];
    int it = NUSERS + ei[e];
    int s1 = atomicAdd(&S[u >> 7], 1);
    pk[s1] = ((unsigned)it << 7) | (unsigned)(u & 127);
    int s2 = atomicAdd(&S[it >> 7], 1);
    pk[s2] = ((unsigned)u << 7) | (unsigned)(it & 127);
  }
}

// Pass 4: one block per bucket (128 nodes). LDS histogram -> deg/ptr/dinv,
// LDS rank into lcol -> coalesced col stream-out. col stores the neighbor's
// OPPOSITE-HALF-LOCAL index. Fused scaled-cast s0 = dinv * G (bf16).
__global__ __launch_bounds__(256) void k_bucket_csr(
    const unsigned* __restrict__ pk, const int* __restrict__ btot,
    const int* __restrict__ bbase, int* __restrict__ deg, int* __restrict__ ptr,
    float* __restrict__ dinv, int* __restrict__ col,
    const float4* __restrict__ Gu4, const float4* __restrict__ Gi4,
    uint2* __restrict__ h0) {
  __shared__ unsigned sitm[BCAP];
  __shared__ int lcol[BCAP];
  __shared__ int ldeg[128], lscan[128], lcnt[128];
  __shared__ float sdv[128];
  int b = blockIdx.x;
  int base = bbase[b];
  int n = btot[b];
  for (int i = threadIdx.x; i < n; i += 256)
    if (i < BCAP) sitm[i] = pk[base + i];
  if (threadIdx.x < 128) { ldeg[threadIdx.x] = 0; lcnt[threadIdx.x] = 0; }
  __syncthreads();
  for (int i = threadIdx.x; i < n; i += 256) {
    unsigned p = (i < BCAP) ? sitm[i] : pk[base + i];
    atomicAdd(&ldeg[p & 127], 1);
  }
  __syncthreads();
  if (threadIdx.x < 128) lscan[threadIdx.x] = ldeg[threadIdx.x];
  __syncthreads();
  for (int off = 1; off < 128; off <<= 1) {
    int t = 0;
    if (threadIdx.x < 128 && (int)threadIdx.x >= off) t = lscan[threadIdx.x - off];
    __syncthreads();
    if (threadIdx.x < 128 && (int)threadIdx.x >= off) lscan[threadIdx.x] += t;
    __syncthreads();
  }
  int node = b * 128 + threadIdx.x;
  if (threadIdx.x < 128) {
    int d = ldeg[threadIdx.x];
    lscan[threadIdx.x] -= d;               // -> exclusive (bucket-local)
    float dv = d > 0 ? rsqrtf((float)d) : 0.0f;
    sdv[threadIdx.x] = dv;
    if (node < NNODES) {
      deg[node] = d;
      ptr[node] = base + lscan[threadIdx.x];
      dinv[node] = dv;
    }
  }
  __syncthreads();
  for (int i = threadIdx.x; i < n; i += 256) {
    unsigned p = (i < BCAP) ? sitm[i] : pk[base + i];
    int dl = p & 127;
    int nb = (int)(p >> 7);                // neighbor global id
    int dnode = b * 128 + dl;
    int val = (dnode < NUSERS) ? nb - NUSERS : nb;   // opposite-half-local id
    int rel = lscan[dl] + atomicAdd(&lcnt[dl], 1);
    if (rel < BCAP) lcol[rel] = val;
    else col[base + rel] = val;            // overflow fallback (rare/never)
  }
  __syncthreads();
  int nf = min(n, BCAP);
  for (int i = threadIdx.x; i < nf; i += 256) col[base + i] = lcol[i];
  // scaled cast: h0 = bf16(dinv * G) for this bucket's 128 nodes
  for (int w = threadIdx.x; w < 128 * 16; w += 256) {
    int nl = w >> 4, q = w & 15;
    int nd = b * 128 + nl;
    if (nd < NNODES) {
      float dv = sdv[nl];
      float4 v = (nd < NUSERS) ? Gu4[(size_t)nd * 16 + q]
                               : Gi4[(size_t)(nd - NUSERS) * 16 + q];
      h0[(size_t)nd * 16 + q] =
          make_uint2(pack2(dv * v.x, dv * v.y), pack2(dv * v.z, dv * v.w));
    }
  }
}

// Scaled-space SpMM: s_out(n) = dinv(n)^2 * sum_{c in N(n)} s_in(c).
__global__ __launch_bounds__(512) void k_spmm2(
    const int* __restrict__ ptr, const int* __restrict__ deg,
    const int* __restrict__ col, const float* __restrict__ dinv,
    const uint4* __restrict__ h, uint4* __restrict__ hout) {
  int t = blockIdx.x * 512 + threadIdx.x;
  int g = t >> 3;
  int q = t & 7;
  if (g >= NNODES) return;
  const uint4* hq = ((g < NUSERS) ? h + (size_t)NUSERS * 8 : h) + q;
  int st = ptr[g], dg = deg[g];
  float dn = dinv[g];
  SPMM_BODY(col, hq, hout, (size_t)g * 8 + q);
}

// Fused: per-block layer-3 SpMM for its own 16 batch elements (48 nodes)
// into 6KB LDS, then gather + layer sum + BPR loss. Block-local dep only.
__global__ __launch_bounds__(256) void k_loss3(
    const int* __restrict__ usr, const int* __restrict__ pos,
    const int* __restrict__ neg, const int* __restrict__ ptr,
    const int* __restrict__ deg, const int* __restrict__ col,
    const float* __restrict__ dinv,
    const float4* __restrict__ Gu4, const float4* __restrict__ Gi4,
    const uint4* __restrict__ h2v, const uint2* __restrict__ h1u,
    const uint2* __restrict__ h2u, float* __restrict__ bpart) {
  __shared__ uint4 sh3[48 * 8];    // 48 node rows x 128B = 6KB
  __shared__ float sL[4], sR[4];
  int bid = blockIdx.x, tid = threadIdx.x;

  // Phase 1: s3 for this block's 48 nodes (8 lanes per node row)
  for (int t = tid; t < 48 * 8; t += 256) {
    int s = t >> 3, q = t & 7;
    int bb = s / 3, role = s - bb * 3;
    int b = bid * 16 + bb;
    int g, coff;
    if (role == 0) { g = usr[b]; coff = NUSERS; }
    else if (role == 1) { g = NUSERS + pos[b]; coff = 0; }
    else { g = NUSERS + neg[b]; coff = 0; }
    const uint4* hq = h2v + (size_t)coff * 8 + q;
    int st = ptr[g], dg = deg[g];
    float dn = dinv[g];
    SPMM_BODY(col, hq, sh3, s * 8 + q);
  }
  __syncthreads();

  // Phase 2: loss; 16 lanes per batch element.
  const uint2* sh3u = (const uint2*)sh3;
  int wid = tid >> 6, lane = tid & 63;
  int bb = tid >> 4, q = tid & 15;
  int b = bid * 16 + bb;
  const float sc = 0.25f;
  int iu = usr[b], ip = pos[b], ig = neg[b];
  float sdu = sqrtf((float)deg[iu]);
  float sdp = sqrtf((float)deg[NUSERS + ip]);
  float sdn = sqrtf((float)deg[NUSERS + ig]);
  size_t ou = (size_t)iu * 16 + q;
  size_t op = ((size_t)NUSERS + ip) * 16 + q;
  size_t on = ((size_t)NUSERS + ig) * 16 + q;
  float4 u = Gu4[ou];
  float4 p = Gi4[(size_t)ip * 16 + q];
  float4 g = Gi4[(size_t)ig * 16 + q];
  float4 su = {0, 0, 0, 0}, sp = {0, 0, 0, 0}, sg = {0, 0, 0, 0};
  uint2 v;
  v = h1u[ou]; su.x += bf_lo(v.x); su.y += bf_hi(v.x); su.z += bf_lo(v.y); su.w += bf_hi(v.y);
  v = h2u[ou]; su.x += bf_lo(v.x); su.y += bf_hi(v.x); su.z += bf_lo(v.y); su.w += bf_hi(v.y);
  v = sh3u[(size_t)(bb * 3 + 0) * 16 + q];
  su.x += bf_lo(v.x); su.y += bf_hi(v.x); su.z += bf_lo(v.y); su.w += bf_hi(v.y);
  v = h1u[op]; sp.x += bf_lo(v.x); sp.y += bf_hi(v.x); sp.z += bf_lo(v.y); sp.w += bf_hi(v.y);
  v = h2u[op]; sp.x += bf_lo(v.x); sp.y += bf_hi(v.x); sp.z += bf_lo(v.y); sp.w += bf_hi(v.y);
  v = sh3u[(size_t)(bb * 3 + 1) * 16 + q];
  sp.x += bf_lo(v.x); sp.y += bf_hi(v.x); sp.z += bf_lo(v.y); sp.w += bf_hi(v.y);
  v = h1u[on]; sg.x += bf_lo(v.x); sg.y += bf_hi(v.x); sg.z += bf_lo(v.y); sg.w += bf_hi(v.y);
  v = h2u[on]; sg.x += bf_lo(v.x); sg.y += bf_hi(v.x); sg.z += bf_lo(v.y); sg.w += bf_hi(v.y);
  v = sh3u[(size_t)(bb * 3 + 2) * 16 + q];
  sg.x += bf_lo(v.x); sg.y += bf_hi(v.x); sg.z += bf_lo(v.y); sg.w += bf_hi(v.y);
  u.x = (u.x + sdu * su.x) * sc; u.y = (u.y + sdu * su.y) * sc;
  u.z = (u.z + sdu * su.z) * sc; u.w = (u.w + sdu * su.w) * sc;
  p.x = (p.x + sdp * sp.x) * sc; p.y = (p.y + sdp * sp.y) * sc;
  p.z = (p.z + sdp * sp.z) * sc; p.w = (p.w + sdp * sp.w) * sc;
  g.x = (g.x + sdn * sg.x) * sc; g.y = (g.y + sdn * sg.y) * sc;
  g.z = (g.z + sdn * sg.z) * sc; g.w = (g.w + sdn * sg.w) * sc;
  float dp = u.x * p.x + u.y * p.y + u.z * p.z + u.w * p.w;
  float dn = u.x * g.x + u.y * g.y + u.z * g.z + u.w * g.w;
  float rg = u.x * u.x + u.y * u.y + u.z * u.z + u.w * u.w
           + p.x * p.x + p.y * p.y + p.z * p.z + p.w * p.w
           + g.x * g.x + g.y * g.y + g.z * g.z + g.w * g.w;
  #pragma unroll
  for (int m = 1; m <= 8; m <<= 1) {
    dp += __shfl_xor(dp, m);
    dn += __shfl_xor(dn, m);
    rg += __shfl_xor(rg, m);
  }
  float accL = 0.0f, accR = 0.0f;
  if (q == 0) {
    float diff = dp - dn;
    accL = -(fminf(diff, 0.0f) - log1pf(expf(-fabsf(diff))));
    accR = rg;
  }
  accL += __shfl_xor(accL, 16); accR += __shfl_xor(accR, 16);
  accL += __shfl_xor(accL, 32); accR += __shfl_xor(accR, 32);
  if (lane == 0) { sL[wid] = accL; sR[wid] = accR; }
  __syncthreads();
  if (tid == 0) {
    bpart[bid] = sL[0] + sL[1] + sL[2] + sL[3];
    bpart[LOSS3_B + bid] = sR[0] + sR[1] + sR[2] + sR[3];
  }
}

__global__ void k_final(const float* __restrict__ bpart, float* __restrict__ out) {
  int lane = threadIdx.x;
  float l = 0.0f, r = 0.0f;
  #pragma unroll
  for (int i = 0; i < LOSS3_B; i += 64) {
    l += bpart[lane + i];
    r += bpart[LOSS3_B + lane + i];
  }
  for (int off = 32; off > 0; off >>= 1) {
    l += __shfl_down(l, off);
    r += __shfl_down(r, off);
  }
  if (lane == 0) out[0] = l * (1.0f / BB) + LW * 0.5f * r * (1.0f / BB);
}

extern "C" void kernel_launch(void* const* d_in, const int* in_sizes, int n_in,
                              void* d_out, int out_size, void* d_ws, size_t ws_size,
                              hipStream_t stream) {
  const float* Gu = (const float*)d_in[0];
  const float* Gi = (const float*)d_in[1];
  const int* eu  = (const int*)d_in[2];
  const int* ei  = (const int*)d_in[3];
  const int* usr = (const int*)d_in[4];
  const int* pos = (const int*)d_in[5];
  const int* neg = (const int*)d_in[6];
  float* out = (float*)d_out;

  // Workspace: deg/ptr/dinv (1.8 MB) + col (9.6 MB) + h0..h2 + build scratch.
  //   pk (4.8 MB) -> h1 alias, cnt matrix (1.5 MB) -> h2 alias,
  //   btot/bbase -> h3 region (dead before loss).
  int* deg    = (int*)d_ws;                  // NN16
  int* ptr    = deg + NN16;                  // NN16
  float* dinv = (float*)(ptr + NN16);        // NN16
  int* col    = (int*)(dinv + NN16);         // E2
  uint2* h0   = (uint2*)(col + E2);          // NNODES*16 uint2 each (19.2 MB)
  uint2* h1   = h0 + (size_t)NNODES * 16;
  uint2* h2   = h1 + (size_t)NNODES * 16;
  uint2* h3   = h2 + (size_t)NNODES * 16;    // build scratch region
  float* bpart = (float*)(h3 + (size_t)NNODES * 16);  // 2*LOSS3_B

  unsigned* pk = (unsigned*)h1;              // E2 (scattered directed edges)
  int* cnt     = (int*)h2;                   // NBUCK * CPAD
  int* btot    = (int*)h3;                   // NBUCK
  int* bbase   = btot + 1280;                // NBUCK

  const float4* Gu4 = (const float4*)Gu;
  const float4* Gi4 = (const float4*)Gi;

  // CSR build via two-level counting sort — zero device-scope atomics.
  k_bcount<<<CHUNKS, 256, 0, stream>>>(eu, ei, cnt);
  k_bscan1<<<CHUNKS, 256, 0, stream>>>(cnt, btot);
  k_bscatter<<<CHUNKS, 256, 0, stream>>>(eu, ei, cnt, btot, bbase, pk);
  k_bucket_csr<<<NBUCK, 256, 0, stream>>>(pk, btot, bbase, deg, ptr, dinv, col,
                                          Gu4, Gi4, h0);

  k_spmm2<<<SPMM_B, 512, 0, stream>>>(ptr, deg, col, dinv,
                                      (const uint4*)h0, (uint4*)h1);
  k_spmm2<<<SPMM_B, 512, 0, stream>>>(ptr, deg, col, dinv,
                                      (const uint4*)h1, (uint4*)h2);

  k_loss3<<<LOSS3_B, 256, 0, stream>>>(usr, pos, neg, ptr, deg, col, dinv,
                                       Gu4, Gi4, (const uint4*)h2,
                                       (const uint2*)h1, (const uint2*)h2, bpart);
  k_final<<<1, 64, 0, stream>>>(bpart, out);
}